// Round 8
// baseline (1068.759 us; speedup 1.0000x reference)
//
#include <hip/hip_runtime.h>

// numpy-fp32 semantics: explicit fmaf only, no implicit contraction.
#pragma clang fp contract(off)

typedef unsigned char u8;
typedef unsigned int u32;

#define TSTEPS 4

// Fused (1x1 conv) + BN + LIF, fp32, bit-exact ascending-k FMA chain.
// Tile: BO=16P outputs x BN=128 n, 256 threads, P x 8 per thread.
// Double-buffered LDS (W transposed [k][o]; X as f32 [k][136] or u8 [k][128]),
// global->reg prefetch of tile i+1 during compute of tile i; SINGLE barrier
// per k-tile (commit(buf^1) only races reads that finished before the
// previous barrier -- proven safe R7).
// NSEL=3: ONE block computes q,k,v from a SINGLE staged x-tile (x LDS traffic
// /3 vs grid-expanded fusion); acc[3][P][8].  u8->f32 via plain C casts
// (hipcc folds to v_cvt_f32_ubyteN; inline asm pinned scheduling, R7 -8us).
// NOTE: no min-waves clause -- a ",2" caps VGPR at 128 -> spills (R4).
// XMODE: 0 = X1 fp32 (BK=32 only; split-n frag q<4 at tx*4, q>=4 at 64+tx*4),
//        1 = X1 u8 spikes (BK=32/64; contiguous 8 at tx*8, ds b64 + cvt).
// HASX2: add u8 X2 to X1 at LDS-commit (fc1: x + attn_out, exact).
// OMODE: 0 = u8 spike out; 1 = fused final out_f32 = (x + ao) + spike.
template <int P, int BK, int XMODE, bool HASX2, int OMODE, int NSEL>
__global__ __launch_bounds__(256) void conv_bn_lif(
    const void* __restrict__ X1v, const u8* __restrict__ X2,
    const float* __restrict__ W0, const float* __restrict__ W1,
    const float* __restrict__ W2, const float* __restrict__ bias,
    const float* __restrict__ bn0, const float* __restrict__ bn1,
    const float* __restrict__ bn2,
    u8* __restrict__ S0, u8* __restrict__ S1, u8* __restrict__ S2,
    const float* __restrict__ Xres, const u8* __restrict__ AOres,
    float* __restrict__ Fout,
    int Bsz, int Cin, int Cout, int N)
{
  constexpr int BO   = 16 * P;       // block o-tile (per weight set)
  constexpr int BN   = 128;          // block n-tile (fixed)
  constexpr int TPRX = 256 / BK;     // X-loader threads per k-row
  constexpr int XPT  = BN / TPRX;    // X elems per thread (f32 or u8)
  constexpr int NXC  = (XMODE == 0) ? XPT / 4 : XPT / 16;  // 16B chunks
  static_assert(XMODE == 1 || (BK == 32 && NXC == 4), "f32 X needs BK=32");
  constexpr int WPT  = BO * BK / 256;  // W elems per thread per set
  constexpr int NW4  = WPT / 4;
  constexpr int TPW  = BK / WPT;       // threads per W o-row
  constexpr int WPAD = (P == 4) ? 4 : (P == 2) ? 2 : 0;
  constexpr int WROW = BO + WPAD;
  constexpr int XROWF = BN + 8;      // f32 X row stride (136)

  const int tid = threadIdx.x;
  const int tx = tid & 15, ty = tid >> 4;
  const int nBase = blockIdx.x * BN, oBase = blockIdx.y * BO, b = blockIdx.z;

  const float* Warr[3]  = {W0, W1, W2};
  const float* bnArr[3] = {bn0, bn1, bn2};
  u8*          Sarr[3]  = {S0, S1, S2};

  const int KT = Cin / BK;
  const int TT = TSTEPS * KT;

  __shared__ __align__(16) float Ws[NSEL][2][BK][WROW];
  __shared__ __align__(16) u8 Xraw[(XMODE == 0) ? (2 * BK * XROWF * 4)
                                                : (2 * BK * BN)];
  __shared__ __align__(16) float BnL[NSEL * BO][4];  // sc, mn, bt, bi

  float* XF = (float*)Xraw;
  u8*    X8 = Xraw;

  // BN constants, correctly-rounded fp32 (double emu exact for add/sqrt/div)
  if (tid < NSEL * BO) {
    const int s = tid / BO, oo = tid % BO, o = oBase + oo;
    const float* bnp = bnArr[s];
    float g  = bnp[0 * Cout + o];
    float be = bnp[1 * Cout + o];
    float m  = bnp[2 * Cout + o];
    float vv = bnp[3 * Cout + o];
    float d_f = (float)((double)vv + (double)1e-5f);
    float s_f = (float)sqrt((double)d_f);
    BnL[tid][0] = (float)((double)g / (double)s_f);
    BnL[tid][1] = m;
    BnL[tid][2] = be;
    BnL[tid][3] = bias ? bias[o] : 0.0f;
  }

  float mem[NSEL][P][8], acc[NSEL][P][8];
  #pragma unroll
  for (int s = 0; s < NSEL; ++s)
    #pragma unroll
    for (int p = 0; p < P; ++p)
      #pragma unroll
      for (int q = 0; q < 8; ++q) { mem[s][p][q] = 0.0f; acc[s][p][q] = 0.0f; }

  // loader coords
  const int xRow = tid / TPRX;            // 0..BK-1
  const int xOff = (tid % TPRX) * XPT;    // elem offset within row
  const int wO   = tid / TPW;             // 0..BO-1
  const int wK   = (tid % TPW) * WPT;     // 0..BK-WPT

  float4 px[NXC];            // XMODE 0 staging (f32)
  uint4  pxu[NXC];           // XMODE 1 staging (u8 bytes)
  u32    pau[4];             // HASX2 staging (16 u8, XMODE0 only)
  float4 pw[NSEL][NW4];      // W staging per set

  auto issue = [&](int i) {
    const int tI = i / KT, k0 = (i % KT) * BK;
    const size_t xb = (size_t)(tI * Bsz + b) * Cin * N
                    + (size_t)(k0 + xRow) * N + nBase + xOff;
    if constexpr (XMODE == 0) {
      const float* xp = (const float*)X1v + xb;
      #pragma unroll
      for (int f = 0; f < NXC; ++f) px[f] = *(const float4*)(xp + 4 * f);
    } else {
      const u8* xp = (const u8*)X1v + xb;
      #pragma unroll
      for (int f = 0; f < NXC; ++f) pxu[f] = *(const uint4*)(xp + 16 * f);
    }
    if constexpr (HASX2) {
      uint4 u = *(const uint4*)(X2 + xb);
      pau[0] = u.x; pau[1] = u.y; pau[2] = u.z; pau[3] = u.w;
    }
    #pragma unroll
    for (int s = 0; s < NSEL; ++s) {
      const size_t wb = (size_t)(oBase + wO) * Cin + k0 + wK;
      #pragma unroll
      for (int f = 0; f < NW4; ++f)
        pw[s][f] = *(const float4*)(Warr[s] + wb + 4 * f);
    }
  };

  auto commit = [&](int bf) {
    if constexpr (XMODE == 0) {
      #pragma unroll
      for (int f = 0; f < NXC; ++f) {
        float4 v = px[f];
        if constexpr (HASX2) {
          u32 a2 = pau[f];
          v.x = v.x + (float)(a2 & 0xffu);
          v.y = v.y + (float)((a2 >> 8) & 0xffu);
          v.z = v.z + (float)((a2 >> 16) & 0xffu);
          v.w = v.w + (float)((a2 >> 24) & 0xffu);
        }
        *(float4*)&XF[((size_t)(bf * BK + xRow)) * XROWF + xOff + 4 * f] = v;
      }
    } else {
      #pragma unroll
      for (int f = 0; f < NXC; ++f)
        *(uint4*)&X8[(size_t)(bf * BK + xRow) * BN + xOff + 16 * f] = pxu[f];
    }
    #pragma unroll
    for (int s = 0; s < NSEL; ++s)
      #pragma unroll
      for (int f = 0; f < NW4; ++f) {
        Ws[s][bf][wK + 4 * f + 0][wO] = pw[s][f].x;
        Ws[s][bf][wK + 4 * f + 1][wO] = pw[s][f].y;
        Ws[s][bf][wK + 4 * f + 2][wO] = pw[s][f].z;
        Ws[s][bf][wK + 4 * f + 3][wO] = pw[s][f].w;
      }
  };

  issue(0);
  commit(0);
  __syncthreads();

  for (int tt = 0; tt < TT; ++tt) {
    const int buf = tt & 1;
    if (tt + 1 < TT) issue(tt + 1);   // overlap global latency with compute

    #pragma unroll
    for (int kk = 0; kk < BK; ++kk) { // ascending k, FMA chain (bit-exact)
      float xa[8];
      if constexpr (XMODE == 0) {
        float4 x0 = *(const float4*)&XF[(size_t)(buf * BK + kk) * XROWF + tx * 4];
        float4 x1 = *(const float4*)&XF[(size_t)(buf * BK + kk) * XROWF + 64 + tx * 4];
        xa[0] = x0.x; xa[1] = x0.y; xa[2] = x0.z; xa[3] = x0.w;
        xa[4] = x1.x; xa[5] = x1.y; xa[6] = x1.z; xa[7] = x1.w;
      } else {
        uint2 u = *(const uint2*)&X8[(size_t)(buf * BK + kk) * BN + tx * 8];
        #pragma unroll
        for (int j = 0; j < 4; ++j) xa[j]     = (float)((u.x >> (8 * j)) & 0xffu);
        #pragma unroll
        for (int j = 0; j < 4; ++j) xa[4 + j] = (float)((u.y >> (8 * j)) & 0xffu);
      }
      float wa[NSEL][P];
      #pragma unroll
      for (int s = 0; s < NSEL; ++s) {
        if constexpr (P == 2) {
          float2 w0 = *(const float2*)&Ws[s][buf][kk][ty * 2];
          wa[s][0] = w0.x; wa[s][1] = w0.y;
        } else {
          float4 w0 = *(const float4*)&Ws[s][buf][kk][ty * P];
          wa[s][0] = w0.x; wa[s][1] = w0.y; wa[s][2] = w0.z; wa[s][3] = w0.w;
          if constexpr (P == 8) {
            float4 w1 = *(const float4*)&Ws[s][buf][kk][ty * P + 4];
            wa[s][4] = w1.x; wa[s][5] = w1.y; wa[s][6] = w1.z; wa[s][7] = w1.w;
          }
        }
      }
      #pragma unroll
      for (int s = 0; s < NSEL; ++s)
        #pragma unroll
        for (int p = 0; p < P; ++p)
          #pragma unroll
          for (int q = 0; q < 8; ++q)
            acc[s][p][q] = fmaf(wa[s][p], xa[q], acc[s][p][q]);
    }

    if ((tt % KT) == KT - 1) {
      // epilogue for timestep t (identical op order to the verified kernel)
      const int t = tt / KT;
      const size_t sbase = (size_t)(t * Bsz + b) * Cout * N;
      #pragma unroll
      for (int s = 0; s < NSEL; ++s) {
        u8* __restrict__ Sout = Sarr[s];
        #pragma unroll
        for (int p = 0; p < P; ++p) {
          const int o = oBase + ty * P + p;
          float4 bv = *(const float4*)&BnL[s * BO + ty * P + p][0];
          bool spk[8];
          #pragma unroll
          for (int q = 0; q < 8; ++q) {
            float y = acc[s][p][q];
            if (bias) y = y + bv.w;
            float t1 = y - bv.y;
            float t2 = t1 * bv.x;
            y = t2 + bv.z;
            float m2 = mem[s][p][q];
            float dd = y - m2;
            m2 = m2 + dd * 0.5f;
            bool sp = (m2 - 0.5f) > 0.0f;
            mem[s][p][q] = sp ? 0.0f : m2;
            spk[q] = sp;
            acc[s][p][q] = 0.0f;
          }
          if constexpr (XMODE == 0) {   // split-n: OMODE==0 only here
            const size_t rb0 = sbase + (size_t)o * N + nBase + tx * 4;
            u32 pk0 = 0, pk1 = 0;
            #pragma unroll
            for (int j = 0; j < 4; ++j) {
              if (spk[j])     pk0 |= (1u << (8 * j));
              if (spk[4 + j]) pk1 |= (1u << (8 * j));
            }
            *(u32*)&Sout[rb0]      = pk0;
            *(u32*)&Sout[rb0 + 64] = pk1;
          } else {
            const size_t rb = sbase + (size_t)o * N + nBase + tx * 8;
            if constexpr (OMODE == 0) {
              u32 pk0 = 0, pk1 = 0;
              #pragma unroll
              for (int j = 0; j < 4; ++j) {
                if (spk[j])     pk0 |= (1u << (8 * j));
                if (spk[4 + j]) pk1 |= (1u << (8 * j));
              }
              *(uint2*)&Sout[rb] = make_uint2(pk0, pk1);
            } else {
              float4 xr0 = *(const float4*)&Xres[rb];
              float4 xr1 = *(const float4*)&Xres[rb + 4];
              uint2 av = *(const uint2*)&AOres[rb];
              float xa4[8] = {xr0.x, xr0.y, xr0.z, xr0.w,
                              xr1.x, xr1.y, xr1.z, xr1.w};
              float o4[8];
              #pragma unroll
              for (int j = 0; j < 4; ++j) {
                float sv = spk[j] ? 1.0f : 0.0f;
                float xn = xa4[j] + (float)((av.x >> (8 * j)) & 0xffu);
                o4[j] = xn + sv;
              }
              #pragma unroll
              for (int j = 0; j < 4; ++j) {
                float sv = spk[4 + j] ? 1.0f : 0.0f;
                float xn = xa4[4 + j] + (float)((av.y >> (8 * j)) & 0xffu);
                o4[4 + j] = xn + sv;
              }
              *(float4*)&Fout[rb]     = make_float4(o4[0], o4[1], o4[2], o4[3]);
              *(float4*)&Fout[rb + 4] = make_float4(o4[4], o4[5], o4[6], o4[7]);
            }
          }
        }
      }
    }

    // single barrier per k-tile (safety: see header)
    if (tt + 1 < TT) commit((tt + 1) & 1);
    __syncthreads();
  }
}

// Attention + attn-LIF, q @ (k^T v): integer-exact (unchanged, verified).
__global__ __launch_bounds__(256) void attn_lif(
    const u8* __restrict__ Qs, const u8* __restrict__ Ks,
    const u8* __restrict__ Vs, u8* __restrict__ Rs,
    int Bsz, int C, int N)
{
  const int tid = threadIdx.x;
  const int h = blockIdx.x & 15;
  const int b = blockIdx.x >> 4;

  __shared__ u8 qs[16][528];
  __shared__ u8 ks[16][528];
  __shared__ u8 vs[16][528];
  __shared__ int Gs[16][17];

  const int eG = tid >> 4;
  const int dG = tid & 15;
  const int dR = tid >> 4;
  const int nR0 = tid & 15;

  float mem[32];
  #pragma unroll
  for (int i = 0; i < 32; ++i) mem[i] = 0.0f;

  for (int t = 0; t < TSTEPS; ++t) {
    __syncthreads();
    const size_t base = ((size_t)(t * Bsz + b) * C + h * 16) * N;
    for (int i = 0; i < 32; ++i) {
      int flat = tid + 256 * i;
      int d = flat >> 9, n = flat & 511;
      size_t g = base + (size_t)d * N + n;
      qs[d][n] = Qs[g];
      ks[d][n] = Ks[g];
      vs[d][n] = Vs[g];
    }
    __syncthreads();

    int gi = 0;
    for (int n = 0; n < 512; ++n)
      gi += (int)ks[eG][n] * (int)vs[dG][n];
    Gs[eG][dG] = gi;
    __syncthreads();

    int Greg[16];
    #pragma unroll
    for (int e = 0; e < 16; ++e) Greg[e] = Gs[e][dR];

    const size_t obase = ((size_t)(t * Bsz + b) * C + h * 16 + dR) * N;
    for (int j = 0; j < 32; ++j) {
      int n = nR0 + 16 * j;
      int ri = 0;
      #pragma unroll
      for (int e = 0; e < 16; ++e)
        ri += qs[e][n] ? Greg[e] : 0;
      float r = (float)ri * 0.0625f;
      float m2 = mem[j];
      float d = r - m2;
      m2 = m2 + d * 0.5f;
      float s = (m2 - 0.5f) > 0.0f ? 1.0f : 0.0f;
      mem[j] = (s > 0.0f) ? 0.0f : m2;
      Rs[obase + n] = (s > 0.0f) ? (u8)1 : (u8)0;
    }
  }
}

extern "C" void kernel_launch(void* const* d_in, const int* in_sizes, int n_in,
                              void* d_out, int out_size, void* d_ws, size_t ws_size,
                              hipStream_t stream)
{
  const float* x     = (const float*)d_in[0];
  const float* q_w   = (const float*)d_in[1];
  const float* q_bn  = (const float*)d_in[2];
  const float* k_w   = (const float*)d_in[3];
  const float* k_bn  = (const float*)d_in[4];
  const float* v_w   = (const float*)d_in[5];
  const float* v_bn  = (const float*)d_in[6];
  const float* p_w   = (const float*)d_in[7];
  const float* p_bn  = (const float*)d_in[8];
  const float* f1_w  = (const float*)d_in[9];
  const float* f1_b  = (const float*)d_in[10];
  const float* f1_bn = (const float*)d_in[11];
  const float* f2_w  = (const float*)d_in[12];
  const float* f2_b  = (const float*)d_in[13];
  const float* f2_bn = (const float*)d_in[14];

  const int T = 4, B = 16, C = 256, N = 512, Hm = 1024;
  const size_t SZ = (size_t)T * B * C * N;  // u8 spike buffers (8.4 MB)

  // Workspace (u8), peak 5*SZ = 41.9 MB; h (4*SZ) overlays dead q/k/v/r.
  char* ws = (char*)d_ws;
  u8* q_s  = (u8*)(ws + 0 * SZ);
  u8* k_s  = (u8*)(ws + 1 * SZ);
  u8* v_s  = (u8*)(ws + 2 * SZ);
  u8* r_s  = (u8*)(ws + 3 * SZ);
  u8* ao_s = (u8*)(ws + 4 * SZ);
  u8* h_s  = (u8*)(ws + 0 * SZ);

  dim3 blk(256);
  dim3 gQKV(N / 128, C / 32, B);   // merged QKV, P=2 -> (4,8,16)=512
  dim3 gP2(N / 128, C / 32, B);    // P=2, Cout=256   -> (4,8,16)=512
  dim3 gF1(N / 128, Hm / 128, B);  // P=8, Cout=1024  -> (4,8,16)=512

  // Merged QKV: one block stages x once, computes q,k,v (x LDS traffic /3).
  conv_bn_lif<2, 32, 0, false, 0, 3><<<gQKV, blk, 0, stream>>>(
      x, nullptr, q_w, k_w, v_w, nullptr, q_bn, k_bn, v_bn,
      q_s, k_s, v_s, nullptr, nullptr, nullptr, B, C, C, N);

  attn_lif<<<dim3(B * 16), blk, 0, stream>>>(q_s, k_s, v_s, r_s, B, C, N);

  conv_bn_lif<2, 64, 1, false, 0, 1><<<gP2, blk, 0, stream>>>(
      r_s, nullptr, p_w, p_w, p_w, nullptr, p_bn, p_bn, p_bn,
      ao_s, ao_s, ao_s, nullptr, nullptr, nullptr, B, C, C, N);
  conv_bn_lif<8, 32, 0, true, 0, 1><<<gF1, blk, 0, stream>>>(
      x, ao_s, f1_w, f1_w, f1_w, f1_b, f1_bn, f1_bn, f1_bn,
      h_s, h_s, h_s, nullptr, nullptr, nullptr, B, C, Hm, N);
  conv_bn_lif<2, 64, 1, false, 1, 1><<<gP2, blk, 0, stream>>>(
      h_s, nullptr, f2_w, f2_w, f2_w, f2_b, f2_bn, f2_bn, f2_bn,
      nullptr, nullptr, nullptr, x, ao_s, (float*)d_out, B, Hm, C, N);
}